// Round 16
// baseline (339.055 us; speedup 1.0000x reference)
//
#include <hip/hip_runtime.h>
#include <hip/hip_bf16.h>

#define NODES 16384
#define FEAT 512
typedef __hip_bfloat16 bf16;
typedef __hip_bfloat162 bf162;
typedef short short8v __attribute__((ext_vector_type(8)));
typedef float f32x4 __attribute__((ext_vector_type(4)));

static __device__ __forceinline__ float b2f(short s){
  return __uint_as_float(((unsigned)(unsigned short)s) << 16);
}
static __device__ __forceinline__ void split_store(bf16* h, bf16* l, size_t i, float v){
  bf16 hi = __float2bfloat16(v);
  h[i] = hi; l[i] = __float2bfloat16(v - __bfloat162float(hi));
}

// ---------------- diagnostic sentinel ----------------
__global__ void sentinel_kernel(float* __restrict__ out, int n, float v){
  int i = blockIdx.x*blockDim.x + threadIdx.x;
  if (i < n) out[i] = v;
}

// ---------------- CSR build ----------------
__global__ void zero_kernel(int* __restrict__ p, int n){
  int i = blockIdx.x*blockDim.x + threadIdx.x;
  if (i < n) p[i] = 0;
}
__global__ void count_kernel(const int* __restrict__ ei, int* __restrict__ counts, int E){
  int i = blockIdx.x*blockDim.x + threadIdx.x;
  if (i < 2*E){
    int dst = (i < E) ? ei[E+i] : ei[i-E];
    atomicAdd(&counts[dst], 1);
  }
}
__global__ __launch_bounds__(1024) void scan_kernel(const int* __restrict__ counts,
                                                    int* __restrict__ offs, int* __restrict__ cursor){
  __shared__ int sh[1024];
  const int t = threadIdx.x;
  int loc[16]; int s = 0;
#pragma unroll
  for (int i=0;i<16;i++){ loc[i] = counts[t*16+i]; s += loc[i]; }
  sh[t] = s; __syncthreads();
  for (int d=1; d<1024; d<<=1){
    int v = (t>=d) ? sh[t-d] : 0;
    __syncthreads(); sh[t] += v; __syncthreads();
  }
  int run = (t==0) ? 0 : sh[t-1];
#pragma unroll
  for (int i=0;i<16;i++){ offs[t*16+i] = run; cursor[t*16+i] = run; run += loc[i]; }
  if (t==1023) offs[NODES] = run;
}
__global__ void fill_kernel(const int* __restrict__ ei, int* __restrict__ cursor,
                            unsigned short* __restrict__ csr, int E){
  int i = blockIdx.x*blockDim.x + threadIdx.x;
  if (i < 2*E){
    int src = ei[i];
    int dst = (i < E) ? ei[E+i] : ei[i-E];
    int pos = atomicAdd(&cursor[dst], 1);
    csr[pos] = (unsigned short)src;
  }
}

// ---------------- prep ----------------
// Big-GEMM inputs (x, W1, W2): single bf16 -- error attenuated by softmax-avg.
// Tail weights (wv, wo, f1, f2): bf16 SPLIT pairs -- no attenuation downstream of agg.
struct PrepArgs {
  const float *x,*W1,*W2,*wv,*wo,*f1,*f2;
  bf16 *xh,*w1h,*w2h,*wvh,*wvl,*woh,*wol,*f1h,*f1l,*f2h,*f2l;
};
__global__ void prep_kernel(PrepArgs P){
  int i = blockIdx.x*blockDim.x + threadIdx.x;
  if (i < 2097152){ P.xh[i] = __float2bfloat16(P.x[i]); return; }
  i -= 2097152;
  if (i < 65536){ P.w1h[i] = __float2bfloat16(P.W1[(i&127)*512 + (i>>7)]); return; }     // 128x512
  i -= 65536;
  if (i < 262144){ P.w2h[i] = __float2bfloat16(P.W2[(i&511)*512 + (i>>9)]); return; }    // 512x512
  i -= 262144;
  if (i < 16384){ split_store(P.wvh, P.wvl, i, P.wv[(i&127)*128 + (i>>7)]); return; }    // 128x128
  i -= 16384;
  if (i < 16384){ split_store(P.woh, P.wol, i, P.wo[(i&127)*128 + (i>>7)]); return; }
  i -= 16384;
  if (i < 65536){ split_store(P.f1h, P.f1l, i, P.f1[(i&127)*512 + (i>>7)]); return; }    // 128x512
  i -= 65536;
  if (i < 65536){ split_store(P.f2h, P.f2l, i, P.f2[(i&511)*128 + (i>>9)]); return; }    // 512x128
}

// ---------------- MFMA GEMM (r12-measured shape): 64x64 per wave ----------------
// grid = (row-bands x, col-strips y): XCD = x%8 -> A row-band stays L2-resident.
static __device__ __forceinline__ short8v ld8(const bf16* p){
  return *(const short8v*)(const void*)(p);
}
template<int K, int SA, int SB, int ACT, int OMODE, int WPB>
__global__ __launch_bounds__(256) void mgemm(
    const bf16* __restrict__ Ah, const bf16* __restrict__ Al,
    const bf16* __restrict__ Bh, const bf16* __restrict__ Bl,
    const float* __restrict__ bias,
    float* __restrict__ Cf, bf16* __restrict__ Ch, bf16* __restrict__ Cl, int N){
  const int l = threadIdx.x & 63, w = threadIdx.x >> 6;
  const int lg = l >> 4, lr = l & 15;
  const int r0 = (blockIdx.x*WPB + w)*64;
  const int c0 = blockIdx.y*64;
  f32x4 acc[4][4] = {};
  int abase[4], bbase[4];
#pragma unroll
  for (int f=0; f<4; f++){
    abase[f] = (r0 + f*16 + lr)*K + lg*8;
    bbase[f] = (c0 + f*16 + lr)*K + lg*8;
  }
#pragma unroll
  for (int k0 = 0; k0 < K; k0 += 32){
    short8v ah[4], alo[4], bh[4], blo[4];
#pragma unroll
    for (int f=0; f<4; f++){
      ah[f] = ld8(Ah + abase[f] + k0);
      if (SA) alo[f] = ld8(Al + abase[f] + k0);
      bh[f] = ld8(Bh + bbase[f] + k0);
      if (SB) blo[f] = ld8(Bl + bbase[f] + k0);
    }
#pragma unroll
    for (int fm=0; fm<4; fm++)
#pragma unroll
      for (int fn=0; fn<4; fn++){
        acc[fm][fn] = __builtin_amdgcn_mfma_f32_16x16x32_bf16(ah[fm], bh[fn], acc[fm][fn], 0,0,0);
        if (SB) acc[fm][fn] = __builtin_amdgcn_mfma_f32_16x16x32_bf16(ah[fm], blo[fn], acc[fm][fn], 0,0,0);
        if (SA) acc[fm][fn] = __builtin_amdgcn_mfma_f32_16x16x32_bf16(alo[fm], bh[fn], acc[fm][fn], 0,0,0);
      }
  }
#pragma unroll
  for (int fm=0; fm<4; fm++){
#pragma unroll
    for (int fn=0; fn<4; fn++){
      const int col = c0 + fn*16 + lr;
      const float bv = bias ? bias[col] : 0.f;
#pragma unroll
      for (int r=0; r<4; r++){
        const int row = r0 + fm*16 + lg*4 + r;
        float v = acc[fm][fn][r] + bv;
        if (ACT==1) v = fmaxf(v, 0.f);
        const size_t idx = (size_t)row*N + col;
        if (OMODE==0) Cf[idx] = v;
        else if (OMODE==1) Ch[idx] = __float2bfloat16(v);
        else split_store(Ch, Cl, idx, v);
      }
    }
  }
}

// ---------------- attention coefficients ----------------
__global__ __launch_bounds__(256) void alsald_kernel(const bf16* __restrict__ h,
    const float* __restrict__ a_s, const float* __restrict__ a_d,
    float* __restrict__ als, float* __restrict__ ald){
  int n = blockIdx.x;
  int w = threadIdx.x >> 6, lane = threadIdx.x & 63;
  int c = w*128 + lane*2;
  bf162 hv = *(const bf162*)&h[(size_t)n*FEAT + c];
  float hx = __bfloat162float(hv.x), hy = __bfloat162float(hv.y);
  float2 as2 = *(const float2*)&a_s[c];
  float2 ad2 = *(const float2*)&a_d[c];
  float s = hx*as2.x + hy*as2.y;
  float d = hx*ad2.x + hy*ad2.y;
#pragma unroll
  for (int o=32;o>0;o>>=1){ s += __shfl_xor(s,o); d += __shfl_xor(d,o); }
  if (lane == 0){ als[n*4+w] = s; ald[n*4+w] = d; }
}

// ---------------- fused GAT aggregation: register-cached alpha + shuffle broadcast ----------------
// phase-2 full pages are STATICALLY unrolled (16 indep gather chains -> MLP hides latency);
// only the (at most one) partial tail page runs the dynamic-bound loop.
template<bool CONCAT>
__global__ __launch_bounds__(256) void gat_fused_kernel(const bf16* __restrict__ hfeat,
    const float* __restrict__ als, const float* __restrict__ ald,
    const int* __restrict__ offs, const unsigned short* __restrict__ csr,
    const float* __restrict__ bias, void* __restrict__ outv,
    bf16* __restrict__ qh, bf16* __restrict__ ql){
  const int w = threadIdx.x >> 6, l = threadIdx.x & 63, g = l >> 4, s16 = l & 15;
  const int nb = blockIdx.x;
  const int n = (nb & 7)*2048 + (nb >> 3)*4 + w;   // cluster-contiguous, XCD-aligned
  const float adg = ald[(size_t)n*4 + g];
  const int beg = offs[n];
  const int cnt = offs[n+1] - beg + 1;             // + implicit self-loop (edge cnt-1)
  // ---- phase 1: per-head-lane e for edges s16+16p ----
  float ev[6]; int sv[6];
#pragma unroll
  for (int p=0;p<6;p++){
    const int i = s16 + p*16;
    int src = n;
    float e = -1e30f;
    if (i < cnt){
      if (i < cnt-1) src = (int)csr[beg+i];
      float t = als[(size_t)src*4+g] + adg;
      e = fmaxf(t, 0.2f*t);                        // leaky_relu 0.2
    }
    ev[p] = e; sv[p] = src;
  }
  float m = -1e30f;
#pragma unroll
  for (int p=0;p<6;p++) m = fmaxf(m, ev[p]);
  float den = 0.f;
#pragma unroll
  for (int p=0;p<6;p++) den += (ev[p] > -1e29f) ? __expf(ev[p]-m) : 0.f;
  // butterfly merge (m,den) within the 16-lane head group
#pragma unroll
  for (int mask=1; mask<16; mask<<=1){
    float mo = __shfl_xor(m, mask);
    float dd = __shfl_xor(den, mask);
    float nm = fmaxf(m, mo);
    den = den*__expf(m-nm) + dd*__expf(mo-nm);
    m = nm;
  }
  const float C = __expf(-m)/(den + 1e-16f);
#pragma unroll
  for (int p=0;p<6;p++) ev[p] = (ev[p] > -1e29f) ? __expf(ev[p])*C : 0.f;  // ev := alpha
  // ---- phase 2: weighted gather; (alpha,src) broadcast via shfl ----
  float acc[8] = {0,0,0,0,0,0,0,0};
  const int fb = l*8;
#pragma unroll
  for (int p=0;p<6;p++){
    const int pbase = p*16;
    if (pbase + 16 <= cnt){
      // full page: static 16-iteration unroll -> 16 independent shfl+gather+FMA chains
#pragma unroll
      for (int j=0;j<16;++j){
        const int sel = (l & 48) | j;
        const float a = __shfl(ev[p], sel);
        const int src = __shfl(sv[p], sel);
        const short8v hv = *(const short8v*)(const void*)&hfeat[(size_t)src*FEAT + fb];
#pragma unroll
        for (int k=0;k<8;k++) acc[k] += a * b2f(hv[k]);
      }
    } else if (pbase < cnt){
      const int lim = cnt - pbase;
      for (int j=0;j<lim;++j){
        const int sel = (l & 48) | j;
        const float a = __shfl(ev[p], sel);
        const int src = __shfl(sv[p], sel);
        const short8v hv = *(const short8v*)(const void*)&hfeat[(size_t)src*FEAT + fb];
#pragma unroll
        for (int k=0;k<8;k++) acc[k] += a * b2f(hv[k]);
      }
    }
  }
  // fallback for cnt > 96 (probabilistically absent; correctness guard)
  for (int i = 96; i < cnt; ++i){
    const int src = (i < cnt-1) ? (int)csr[beg+i] : n;
    float t = als[(size_t)src*4+g] + adg;
    t = fmaxf(t, 0.2f*t);
    const float a = __expf(t)*C;
    const short8v hv = *(const short8v*)(const void*)&hfeat[(size_t)src*FEAT + fb];
#pragma unroll
    for (int k=0;k<8;k++) acc[k] += a * b2f(hv[k]);
  }
  if (CONCAT){
    short8v ov;
#pragma unroll
    for (int j=0;j<8;j++){
      float v = acc[j] + bias[fb+j];
      v = v > 0.f ? v : expm1f(v);               // fused ELU
      bf16 bv = __float2bfloat16(v);
      ov[j] = (short)*(unsigned short*)&bv;
    }
    *(short8v*)((char*)outv + ((size_t)n*FEAT + fb)*2) = ov;
  } else {
#pragma unroll
    for (int j=0;j<8;j++){
      acc[j] += __shfl_xor(acc[j], 16);
      acc[j] += __shfl_xor(acc[j], 32);
    }
    if (l < 16){
      float* op = (float*)outv + (size_t)n*128 + l*8;
#pragma unroll
      for (int j=0;j<8;j++){
        const int col = l*8 + j;
        float v = 0.25f*acc[j] + bias[col];
        // fused pe[L-1] add + q bf16-split
        float ex = __expf((float)(col & ~1) * (-9.210340371976184f/128.f));
        float pe = (col & 1) ? cosf(4.f*ex) : sinf(4.f*ex);
        float q = v + pe;
        op[j] = q;
        split_store(qh, ql, (size_t)n*128 + col, q);
      }
    }
  }
}

// ---------------- LayerNorm(a+b), optional bf16 split output ----------------
template<int SPLIT>
__global__ __launch_bounds__(256) void ln_kernel(const float* __restrict__ a, const float* __restrict__ b,
    const float* __restrict__ g, const float* __restrict__ bb, float* __restrict__ out,
    bf16* __restrict__ oh, bf16* __restrict__ ol){
  int row = blockIdx.x*4 + (threadIdx.x >> 6);
  int lane = threadIdx.x & 63;
  int c = lane*2;
  float2 va = *(const float2*)&a[(size_t)row*128 + c];
  float2 vb = *(const float2*)&b[(size_t)row*128 + c];
  float x0 = va.x+vb.x, x1 = va.y+vb.y;
  float s = x0+x1, q = x0*x0 + x1*x1;
#pragma unroll
  for (int o=32;o>0;o>>=1){ s += __shfl_xor(s,o); q += __shfl_xor(q,o); }
  float mu = s*(1.f/128.f);
  float var = q*(1.f/128.f) - mu*mu;
  float r = 1.f/sqrtf(var + 1e-5f);
  float y0 = (x0-mu)*r*g[c]   + bb[c];
  float y1 = (x1-mu)*r*g[c+1] + bb[c+1];
  size_t idx = (size_t)row*128 + c;
  out[idx] = y0; out[idx+1] = y1;
  if (SPLIT){ split_store(oh, ol, idx, y0); split_store(oh, ol, idx+1, y1); }
}

// ---------------- fused LayerNorm2 + classifier head ----------------
__global__ __launch_bounds__(256) void ln_final_kernel(const float* __restrict__ a, const float* __restrict__ b,
    const float* __restrict__ g, const float* __restrict__ bb,
    const float* __restrict__ wc, const float* __restrict__ bc,
    float* __restrict__ out){
  int row = blockIdx.x*4 + (threadIdx.x >> 6);
  int lane = threadIdx.x & 63;
  int c = lane*2;
  float2 va = *(const float2*)&a[(size_t)row*128 + c];
  float2 vb = *(const float2*)&b[(size_t)row*128 + c];
  float x0 = va.x+vb.x, x1 = va.y+vb.y;
  float s = x0+x1, q = x0*x0 + x1*x1;
#pragma unroll
  for (int o=32;o>0;o>>=1){ s += __shfl_xor(s,o); q += __shfl_xor(q,o); }
  float mu = s*(1.f/128.f);
  float var = q*(1.f/128.f) - mu*mu;
  float r = 1.f/sqrtf(var + 1e-5f);
  float y0 = (x0-mu)*r*g[c]   + bb[c];
  float y1 = (x1-mu)*r*g[c+1] + bb[c+1];
  float s0 = y0*wc[c*2]   + y1*wc[(c+1)*2];
  float s1 = y0*wc[c*2+1] + y1*wc[(c+1)*2+1];
#pragma unroll
  for (int o=32;o>0;o>>=1){ s0 += __shfl_xor(s0,o); s1 += __shfl_xor(s1,o); }
  if (lane == 0){
    out[row*2]   = s0 + bc[0];
    out[row*2+1] = s1 + bc[1];
  }
}

extern "C" void kernel_launch(void* const* d_in, const int* in_sizes, int n_in,
                              void* d_out, int out_size, void* d_ws, size_t ws_size,
                              hipStream_t stream){
  const float* x      = (const float*)d_in[0];
  const int*   ei     = (const int*)d_in[1];
  const float* W1     = (const float*)d_in[3];
  const float* a_src1 = (const float*)d_in[4];
  const float* a_dst1 = (const float*)d_in[5];
  const float* b1     = (const float*)d_in[6];
  const float* W2     = (const float*)d_in[7];
  const float* a_src2 = (const float*)d_in[8];
  const float* a_dst2 = (const float*)d_in[9];
  const float* b2     = (const float*)d_in[10];
  const float* wv     = (const float*)d_in[15];
  const float* bv     = (const float*)d_in[16];
  const float* wo     = (const float*)d_in[17];
  const float* bo     = (const float*)d_in[18];
  const float* ln_g   = (const float*)d_in[19];
  const float* ln_b   = (const float*)d_in[20];
  const float* f1     = (const float*)d_in[21];
  const float* fb1    = (const float*)d_in[22];
  const float* f2     = (const float*)d_in[23];
  const float* fb2    = (const float*)d_in[24];
  const float* wc     = (const float*)d_in[25];
  const float* bc     = (const float*)d_in[26];
  float* outp = (float*)d_out;

  const int E = in_sizes[1] / 2;
  const int n = NODES;
  const int tE = 2*E;
  const size_t MB = 1024*1024;

  const size_t NEED = 36*MB;
  if (ws_size < NEED){
    sentinel_kernel<<<(out_size+255)/256, 256, 0, stream>>>(outp, out_size,
        1000.0f + (float)(ws_size / MB));
    return;
  }

  // ---- arena [0,36) MB; liveness audited phase-by-phase ----
  char* base = (char*)d_ws;
  int* counts = (int*)(base + 0);            // [0,64K)   pre-gemm1 only
  int* cursor = (int*)(base + 65536);        // [64K,128K)
  bf16*  h1    = (bf16*)(base + 0);          // [0,16)   gemm1 out -> agg1
  bf16*  xh    = (bf16*)(base + 16*MB);      // [16,20)  prep -> gemm1
  bf16*  h     = (bf16*)(base + 16*MB);      // [16,32)  agg1 out (xh dead) -> gemm2
  bf16*  h2f   = (bf16*)(base + 0);          // [0,16)   gemm2 out (h1 dead) -> agg2
  float* h2q   = (float*)(base + 16*MB);     // [16,24)  agg2 out f32 (h dead) -> ln1
  bf16*  qh    = (bf16*)(base + 24*MB);      // [24,28)  agg2 epilogue -> wv
  bf16*  ql    = (bf16*)(base + 28*MB);      // [28,32)
  bf16*  vh    = (bf16*)(base + 0);          // [0,4)    (h2f dead after agg2)
  bf16*  vl    = (bf16*)(base + 4*MB);       // [4,8)
  float* aobuf = (float*)(base + 8*MB);      // [8,16)
  float* y1    = (float*)(base + 24*MB);     // [24,32)  ln1 out (qh/ql dead after wv)
  bf16*  y1h   = (bf16*)(base + 0);          // [0,4)    (vh/vl dead after wo)
  bf16*  y1l   = (bf16*)(base + 4*MB);       // [4,8)
  bf16*  hidden= (bf16*)(base + 8*MB);       // [8,24)   16MB (aobuf,h2q dead after ln1)
  float* ffn2f = (float*)(base + 0);         // [0,8)    (y1h/l dead after ffn1)
  // S region [32,36): ~3.0 MB
  char* u = base + 32*MB;
  bf16* w1h = (bf16*)u; u += 131072;
  bf16* w2h = (bf16*)u; u += 524288;
  bf16* wvh = (bf16*)u; u += 32768;   bf16* wvl = (bf16*)u; u += 32768;
  bf16* woh = (bf16*)u; u += 32768;   bf16* wol = (bf16*)u; u += 32768;
  bf16* f1h = (bf16*)u; u += 131072;  bf16* f1l = (bf16*)u; u += 131072;
  bf16* f2h = (bf16*)u; u += 131072;  bf16* f2l = (bf16*)u; u += 131072;
  float* als  = (float*)u; u += (size_t)n*4*4;
  float* ald  = (float*)u; u += (size_t)n*4*4;
  int* offs   = (int*)u;   u += (size_t)(n+1)*4 + 252;
  unsigned short* csr = (unsigned short*)u; u += (size_t)tE*2;

  // ---- prep + CSR ----
  PrepArgs P = { x,W1,W2,wv,wo,f1,f2, xh,w1h,w2h,wvh,wvl,woh,wol,f1h,f1l,f2h,f2l };
  prep_kernel<<<(2588672+255)/256, 256, 0, stream>>>(P);
  zero_kernel<<<(n+255)/256, 256, 0, stream>>>(counts, n);
  count_kernel<<<(tE+255)/256, 256, 0, stream>>>(ei, counts, E);
  scan_kernel<<<1, 1024, 0, stream>>>(counts, offs, cursor);
  fill_kernel<<<(tE+255)/256, 256, 0, stream>>>(ei, cursor, csr, E);

  // ---- GAT layer 1 (single-bf16 operands; error attenuated by aggregation) ----
  mgemm<128,0,0,0,1,4><<<dim3(64,8), 256, 0, stream>>>(xh, nullptr, w1h, nullptr, nullptr, nullptr, h1, nullptr, 512);
  alsald_kernel<<<n, 256, 0, stream>>>(h1, a_src1, a_dst1, als, ald);
  gat_fused_kernel<true><<<n/4, 256, 0, stream>>>(h1, als, ald, offs, csr, b1, h, nullptr, nullptr);

  // ---- GAT layer 2 (single-bf16 operands) ----
  mgemm<512,0,0,0,1,4><<<dim3(64,8), 256, 0, stream>>>(h, nullptr, w2h, nullptr, nullptr, nullptr, h2f, nullptr, 512);
  alsald_kernel<<<n, 256, 0, stream>>>(h2f, a_src2, a_dst2, als, ald);
  gat_fused_kernel<false><<<n/4, 256, 0, stream>>>(h2f, als, ald, offs, csr, b2, h2q, qh, ql);

  // ---- temporal attention (collapsed to V at l=L-1) + head: split-precision tail ----
  mgemm<128,1,1,0,2,2><<<dim3(128,2), 128, 0, stream>>>(qh, ql, wvh, wvl, bv, nullptr, vh, vl, 128);
  mgemm<128,1,1,0,0,2><<<dim3(128,2), 128, 0, stream>>>(vh, vl, woh, wol, bo, aobuf, nullptr, nullptr, 128);
  ln_kernel<1><<<n/4, 256, 0, stream>>>(h2q, aobuf, ln_g, ln_b, y1, y1h, y1l);
  mgemm<128,1,1,1,1,4><<<dim3(64,8), 256, 0, stream>>>(y1h, y1l, f1h, f1l, fb1, nullptr, hidden, nullptr, 512);
  mgemm<512,0,1,0,0,2><<<dim3(128,2), 128, 0, stream>>>(hidden, nullptr, f2h, f2l, fb2, ffn2f, nullptr, nullptr, 128);
  ln_final_kernel<<<n/4, 256, 0, stream>>>(y1, ffn2f, ln_g, ln_b, wc, bc, outp);
}

// Round 17
// 318.835 us; speedup vs baseline: 1.0634x; 1.0634x over previous
//
#include <hip/hip_runtime.h>
#include <hip/hip_bf16.h>

#define NODES 16384
#define FEAT 512
typedef __hip_bfloat16 bf16;
typedef __hip_bfloat162 bf162;
typedef short short8v __attribute__((ext_vector_type(8)));
typedef float f32x4 __attribute__((ext_vector_type(4)));

static __device__ __forceinline__ float b2f(short s){
  return __uint_as_float(((unsigned)(unsigned short)s) << 16);
}
static __device__ __forceinline__ void split_store(bf16* h, bf16* l, size_t i, float v){
  bf16 hi = __float2bfloat16(v);
  h[i] = hi; l[i] = __float2bfloat16(v - __bfloat162float(hi));
}

// ---------------- diagnostic sentinel ----------------
__global__ void sentinel_kernel(float* __restrict__ out, int n, float v){
  int i = blockIdx.x*blockDim.x + threadIdx.x;
  if (i < n) out[i] = v;
}

// ---------------- CSR build ----------------
__global__ void zero_kernel(int* __restrict__ p, int n){
  int i = blockIdx.x*blockDim.x + threadIdx.x;
  if (i < n) p[i] = 0;
}
__global__ void count_kernel(const int* __restrict__ ei, int* __restrict__ counts, int E){
  int i = blockIdx.x*blockDim.x + threadIdx.x;
  if (i < 2*E){
    int dst = (i < E) ? ei[E+i] : ei[i-E];
    atomicAdd(&counts[dst], 1);
  }
}
__global__ __launch_bounds__(1024) void scan_kernel(const int* __restrict__ counts,
                                                    int* __restrict__ offs, int* __restrict__ cursor){
  __shared__ int sh[1024];
  const int t = threadIdx.x;
  int loc[16]; int s = 0;
#pragma unroll
  for (int i=0;i<16;i++){ loc[i] = counts[t*16+i]; s += loc[i]; }
  sh[t] = s; __syncthreads();
  for (int d=1; d<1024; d<<=1){
    int v = (t>=d) ? sh[t-d] : 0;
    __syncthreads(); sh[t] += v; __syncthreads();
  }
  int run = (t==0) ? 0 : sh[t-1];
#pragma unroll
  for (int i=0;i<16;i++){ offs[t*16+i] = run; cursor[t*16+i] = run; run += loc[i]; }
  if (t==1023) offs[NODES] = run;
}
__global__ void fill_kernel(const int* __restrict__ ei, int* __restrict__ cursor,
                            unsigned short* __restrict__ csr, int E){
  int i = blockIdx.x*blockDim.x + threadIdx.x;
  if (i < 2*E){
    int src = ei[i];
    int dst = (i < E) ? ei[E+i] : ei[i-E];
    int pos = atomicAdd(&cursor[dst], 1);
    csr[pos] = (unsigned short)src;
  }
}

// ---------------- prep ----------------
// Big-GEMM inputs (x, W1, W2): single bf16 -- error attenuated by softmax-avg.
// Tail weights (wv, wo, f1, f2): bf16 SPLIT pairs -- no attenuation downstream of agg.
struct PrepArgs {
  const float *x,*W1,*W2,*wv,*wo,*f1,*f2;
  bf16 *xh,*w1h,*w2h,*wvh,*wvl,*woh,*wol,*f1h,*f1l,*f2h,*f2l;
};
__global__ void prep_kernel(PrepArgs P){
  int i = blockIdx.x*blockDim.x + threadIdx.x;
  if (i < 2097152){ P.xh[i] = __float2bfloat16(P.x[i]); return; }
  i -= 2097152;
  if (i < 65536){ P.w1h[i] = __float2bfloat16(P.W1[(i&127)*512 + (i>>7)]); return; }     // 128x512
  i -= 65536;
  if (i < 262144){ P.w2h[i] = __float2bfloat16(P.W2[(i&511)*512 + (i>>9)]); return; }    // 512x512
  i -= 262144;
  if (i < 16384){ split_store(P.wvh, P.wvl, i, P.wv[(i&127)*128 + (i>>7)]); return; }    // 128x128
  i -= 16384;
  if (i < 16384){ split_store(P.woh, P.wol, i, P.wo[(i&127)*128 + (i>>7)]); return; }
  i -= 16384;
  if (i < 65536){ split_store(P.f1h, P.f1l, i, P.f1[(i&127)*512 + (i>>7)]); return; }    // 128x512
  i -= 65536;
  if (i < 65536){ split_store(P.f2h, P.f2l, i, P.f2[(i&511)*128 + (i>>9)]); return; }    // 512x128
}

// ---------------- MFMA GEMM (r12-measured shape): 64x64 per wave ----------------
// grid = (row-bands x, col-strips y): XCD = x%8 -> A row-band stays L2-resident.
static __device__ __forceinline__ short8v ld8(const bf16* p){
  return *(const short8v*)(const void*)(p);
}
template<int K, int SA, int SB, int ACT, int OMODE, int WPB>
__global__ __launch_bounds__(256) void mgemm(
    const bf16* __restrict__ Ah, const bf16* __restrict__ Al,
    const bf16* __restrict__ Bh, const bf16* __restrict__ Bl,
    const float* __restrict__ bias,
    float* __restrict__ Cf, bf16* __restrict__ Ch, bf16* __restrict__ Cl, int N){
  const int l = threadIdx.x & 63, w = threadIdx.x >> 6;
  const int lg = l >> 4, lr = l & 15;
  const int r0 = (blockIdx.x*WPB + w)*64;
  const int c0 = blockIdx.y*64;
  f32x4 acc[4][4] = {};
  int abase[4], bbase[4];
#pragma unroll
  for (int f=0; f<4; f++){
    abase[f] = (r0 + f*16 + lr)*K + lg*8;
    bbase[f] = (c0 + f*16 + lr)*K + lg*8;
  }
#pragma unroll
  for (int k0 = 0; k0 < K; k0 += 32){
    short8v ah[4], alo[4], bh[4], blo[4];
#pragma unroll
    for (int f=0; f<4; f++){
      ah[f] = ld8(Ah + abase[f] + k0);
      if (SA) alo[f] = ld8(Al + abase[f] + k0);
      bh[f] = ld8(Bh + bbase[f] + k0);
      if (SB) blo[f] = ld8(Bl + bbase[f] + k0);
    }
#pragma unroll
    for (int fm=0; fm<4; fm++)
#pragma unroll
      for (int fn=0; fn<4; fn++){
        acc[fm][fn] = __builtin_amdgcn_mfma_f32_16x16x32_bf16(ah[fm], bh[fn], acc[fm][fn], 0,0,0);
        if (SB) acc[fm][fn] = __builtin_amdgcn_mfma_f32_16x16x32_bf16(ah[fm], blo[fn], acc[fm][fn], 0,0,0);
        if (SA) acc[fm][fn] = __builtin_amdgcn_mfma_f32_16x16x32_bf16(alo[fm], bh[fn], acc[fm][fn], 0,0,0);
      }
  }
#pragma unroll
  for (int fm=0; fm<4; fm++){
#pragma unroll
    for (int fn=0; fn<4; fn++){
      const int col = c0 + fn*16 + lr;
      const float bv = bias ? bias[col] : 0.f;
#pragma unroll
      for (int r=0; r<4; r++){
        const int row = r0 + fm*16 + lg*4 + r;
        float v = acc[fm][fn][r] + bv;
        if (ACT==1) v = fmaxf(v, 0.f);
        const size_t idx = (size_t)row*N + col;
        if (OMODE==0) Cf[idx] = v;
        else if (OMODE==1) Ch[idx] = __float2bfloat16(v);
        else split_store(Ch, Cl, idx, v);
      }
    }
  }
}

// ---------------- attention coefficients ----------------
__global__ __launch_bounds__(256) void alsald_kernel(const bf16* __restrict__ h,
    const float* __restrict__ a_s, const float* __restrict__ a_d,
    float* __restrict__ als, float* __restrict__ ald){
  int n = blockIdx.x;
  int w = threadIdx.x >> 6, lane = threadIdx.x & 63;
  int c = w*128 + lane*2;
  bf162 hv = *(const bf162*)&h[(size_t)n*FEAT + c];
  float hx = __bfloat162float(hv.x), hy = __bfloat162float(hv.y);
  float2 as2 = *(const float2*)&a_s[c];
  float2 ad2 = *(const float2*)&a_d[c];
  float s = hx*as2.x + hy*as2.y;
  float d = hx*ad2.x + hy*ad2.y;
#pragma unroll
  for (int o=32;o>0;o>>=1){ s += __shfl_xor(s,o); d += __shfl_xor(d,o); }
  if (lane == 0){ als[n*4+w] = s; ald[n*4+w] = d; }
}

// ---------------- fused GAT aggregation ----------------
// phase 1: register-cached alpha per owning lane (r15 structure).
// phase 2: alpha packed to (bf16<<16)|src -> ONE shfl per edge; 2-deep manual pipeline
// (next edge's shfl+gather issued before current edge's FMAs). Dynamic loops (no bloat).
template<bool CONCAT>
__global__ __launch_bounds__(256) void gat_fused_kernel(const bf16* __restrict__ hfeat,
    const float* __restrict__ als, const float* __restrict__ ald,
    const int* __restrict__ offs, const unsigned short* __restrict__ csr,
    const float* __restrict__ bias, void* __restrict__ outv,
    bf16* __restrict__ qh, bf16* __restrict__ ql){
  const int w = threadIdx.x >> 6, l = threadIdx.x & 63, g = l >> 4, s16 = l & 15;
  const int nb = blockIdx.x;
  const int n = (nb & 7)*2048 + (nb >> 3)*4 + w;   // cluster-contiguous, XCD-aligned
  const float adg = ald[(size_t)n*4 + g];
  const int beg = offs[n];
  const int cnt = offs[n+1] - beg + 1;             // + implicit self-loop (edge cnt-1)
  // ---- phase 1: per-head-lane e for edges s16+16p ----
  float ev[6]; int sv[6];
#pragma unroll
  for (int p=0;p<6;p++){
    const int i = s16 + p*16;
    int src = n;
    float e = -1e30f;
    if (i < cnt){
      if (i < cnt-1) src = (int)csr[beg+i];
      float t = als[(size_t)src*4+g] + adg;
      e = fmaxf(t, 0.2f*t);                        // leaky_relu 0.2
    }
    ev[p] = e; sv[p] = src;
  }
  float m = -1e30f;
#pragma unroll
  for (int p=0;p<6;p++) m = fmaxf(m, ev[p]);
  float den = 0.f;
#pragma unroll
  for (int p=0;p<6;p++) den += (ev[p] > -1e29f) ? __expf(ev[p]-m) : 0.f;
  // butterfly merge (m,den) within the 16-lane head group
#pragma unroll
  for (int mask=1; mask<16; mask<<=1){
    float mo = __shfl_xor(m, mask);
    float dd = __shfl_xor(den, mask);
    float nm = fmaxf(m, mo);
    den = den*__expf(m-nm) + dd*__expf(mo-nm);
    m = nm;
  }
  const float C = __expf(-m)/(den + 1e-16f);
  // pack: hi16 = bf16(alpha), lo16 = src
  int pk[6];
#pragma unroll
  for (int p=0;p<6;p++){
    float a = (ev[p] > -1e29f) ? __expf(ev[p])*C : 0.f;
    bf16 ab = __float2bfloat16(a);
    pk[p] = ((int)*(unsigned short*)&ab << 16) | (sv[p] & 0xFFFF);
  }
  // ---- phase 2: weighted gather; packed (alpha,src) broadcast via ONE shfl; 2-deep pipeline ----
  float acc[8] = {0,0,0,0,0,0,0,0};
  const int fb = l*8;
  const bf16* hp = hfeat + fb;
#pragma unroll
  for (int p=0;p<6;p++){
    const int pbase = p*16;
    if (pbase < cnt){
      const int lim = (cnt - pbase < 16) ? (cnt - pbase) : 16;
      int u_c = __shfl(pk[p], (l & 48));
      short8v hv_c = *(const short8v*)(const void*)(hp + (size_t)(u_c & 0xFFFF)*FEAT);
      for (int j=1; j<lim; ++j){
        const int u_n = __shfl(pk[p], (l & 48) | j);
        const short8v hv_n = *(const short8v*)(const void*)(hp + (size_t)(u_n & 0xFFFF)*FEAT);
        const float a_c = __uint_as_float((unsigned)u_c & 0xFFFF0000u);
#pragma unroll
        for (int k=0;k<8;k++) acc[k] += a_c * b2f(hv_c[k]);
        u_c = u_n; hv_c = hv_n;
      }
      const float a_c = __uint_as_float((unsigned)u_c & 0xFFFF0000u);
#pragma unroll
      for (int k=0;k<8;k++) acc[k] += a_c * b2f(hv_c[k]);
    }
  }
  // fallback for cnt > 96 (probabilistically absent; correctness guard)
  for (int i = 96; i < cnt; ++i){
    const int src = (i < cnt-1) ? (int)csr[beg+i] : n;
    float t = als[(size_t)src*4+g] + adg;
    t = fmaxf(t, 0.2f*t);
    const float a = __expf(t)*C;
    const short8v hv = *(const short8v*)(const void*)&hfeat[(size_t)src*FEAT + fb];
#pragma unroll
    for (int k=0;k<8;k++) acc[k] += a * b2f(hv[k]);
  }
  if (CONCAT){
    short8v ov;
#pragma unroll
    for (int j=0;j<8;j++){
      float v = acc[j] + bias[fb+j];
      v = v > 0.f ? v : expm1f(v);               // fused ELU
      bf16 bv = __float2bfloat16(v);
      ov[j] = (short)*(unsigned short*)&bv;
    }
    *(short8v*)((char*)outv + ((size_t)n*FEAT + fb)*2) = ov;
  } else {
#pragma unroll
    for (int j=0;j<8;j++){
      acc[j] += __shfl_xor(acc[j], 16);
      acc[j] += __shfl_xor(acc[j], 32);
    }
    if (l < 16){
      float* op = (float*)outv + (size_t)n*128 + l*8;
#pragma unroll
      for (int j=0;j<8;j++){
        const int col = l*8 + j;
        float v = 0.25f*acc[j] + bias[col];
        // fused pe[L-1] add + q bf16-split
        float ex = __expf((float)(col & ~1) * (-9.210340371976184f/128.f));
        float pe = (col & 1) ? cosf(4.f*ex) : sinf(4.f*ex);
        float q = v + pe;
        op[j] = q;
        split_store(qh, ql, (size_t)n*128 + col, q);
      }
    }
  }
}

// ---------------- LayerNorm(a+b), optional bf16 split output ----------------
template<int SPLIT>
__global__ __launch_bounds__(256) void ln_kernel(const float* __restrict__ a, const float* __restrict__ b,
    const float* __restrict__ g, const float* __restrict__ bb, float* __restrict__ out,
    bf16* __restrict__ oh, bf16* __restrict__ ol){
  int row = blockIdx.x*4 + (threadIdx.x >> 6);
  int lane = threadIdx.x & 63;
  int c = lane*2;
  float2 va = *(const float2*)&a[(size_t)row*128 + c];
  float2 vb = *(const float2*)&b[(size_t)row*128 + c];
  float x0 = va.x+vb.x, x1 = va.y+vb.y;
  float s = x0+x1, q = x0*x0 + x1*x1;
#pragma unroll
  for (int o=32;o>0;o>>=1){ s += __shfl_xor(s,o); q += __shfl_xor(q,o); }
  float mu = s*(1.f/128.f);
  float var = q*(1.f/128.f) - mu*mu;
  float r = 1.f/sqrtf(var + 1e-5f);
  float y0 = (x0-mu)*r*g[c]   + bb[c];
  float y1 = (x1-mu)*r*g[c+1] + bb[c+1];
  size_t idx = (size_t)row*128 + c;
  out[idx] = y0; out[idx+1] = y1;
  if (SPLIT){ split_store(oh, ol, idx, y0); split_store(oh, ol, idx+1, y1); }
}

// ---------------- fused LayerNorm2 + classifier head ----------------
__global__ __launch_bounds__(256) void ln_final_kernel(const float* __restrict__ a, const float* __restrict__ b,
    const float* __restrict__ g, const float* __restrict__ bb,
    const float* __restrict__ wc, const float* __restrict__ bc,
    float* __restrict__ out){
  int row = blockIdx.x*4 + (threadIdx.x >> 6);
  int lane = threadIdx.x & 63;
  int c = lane*2;
  float2 va = *(const float2*)&a[(size_t)row*128 + c];
  float2 vb = *(const float2*)&b[(size_t)row*128 + c];
  float x0 = va.x+vb.x, x1 = va.y+vb.y;
  float s = x0+x1, q = x0*x0 + x1*x1;
#pragma unroll
  for (int o=32;o>0;o>>=1){ s += __shfl_xor(s,o); q += __shfl_xor(q,o); }
  float mu = s*(1.f/128.f);
  float var = q*(1.f/128.f) - mu*mu;
  float r = 1.f/sqrtf(var + 1e-5f);
  float y0 = (x0-mu)*r*g[c]   + bb[c];
  float y1 = (x1-mu)*r*g[c+1] + bb[c+1];
  float s0 = y0*wc[c*2]   + y1*wc[(c+1)*2];
  float s1 = y0*wc[c*2+1] + y1*wc[(c+1)*2+1];
#pragma unroll
  for (int o=32;o>0;o>>=1){ s0 += __shfl_xor(s0,o); s1 += __shfl_xor(s1,o); }
  if (lane == 0){
    out[row*2]   = s0 + bc[0];
    out[row*2+1] = s1 + bc[1];
  }
}

extern "C" void kernel_launch(void* const* d_in, const int* in_sizes, int n_in,
                              void* d_out, int out_size, void* d_ws, size_t ws_size,
                              hipStream_t stream){
  const float* x      = (const float*)d_in[0];
  const int*   ei     = (const int*)d_in[1];
  const float* W1     = (const float*)d_in[3];
  const float* a_src1 = (const float*)d_in[4];
  const float* a_dst1 = (const float*)d_in[5];
  const float* b1     = (const float*)d_in[6];
  const float* W2     = (const float*)d_in[7];
  const float* a_src2 = (const float*)d_in[8];
  const float* a_dst2 = (const float*)d_in[9];
  const float* b2     = (const float*)d_in[10];
  const float* wv     = (const float*)d_in[15];
  const float* bv     = (const float*)d_in[16];
  const float* wo     = (const float*)d_in[17];
  const float* bo     = (const float*)d_in[18];
  const float* ln_g   = (const float*)d_in[19];
  const float* ln_b   = (const float*)d_in[20];
  const float* f1     = (const float*)d_in[21];
  const float* fb1    = (const float*)d_in[22];
  const float* f2     = (const float*)d_in[23];
  const float* fb2    = (const float*)d_in[24];
  const float* wc     = (const float*)d_in[25];
  const float* bc     = (const float*)d_in[26];
  float* outp = (float*)d_out;

  const int E = in_sizes[1] / 2;
  const int n = NODES;
  const int tE = 2*E;
  const size_t MB = 1024*1024;

  const size_t NEED = 36*MB;
  if (ws_size < NEED){
    sentinel_kernel<<<(out_size+255)/256, 256, 0, stream>>>(outp, out_size,
        1000.0f + (float)(ws_size / MB));
    return;
  }

  // ---- arena [0,36) MB; liveness audited phase-by-phase ----
  char* base = (char*)d_ws;
  int* counts = (int*)(base + 0);            // [0,64K)   pre-gemm1 only
  int* cursor = (int*)(base + 65536);        // [64K,128K)
  bf16*  h1    = (bf16*)(base + 0);          // [0,16)   gemm1 out -> agg1
  bf16*  xh    = (bf16*)(base + 16*MB);      // [16,20)  prep -> gemm1
  bf16*  h     = (bf16*)(base + 16*MB);      // [16,32)  agg1 out (xh dead) -> gemm2
  bf16*  h2f   = (bf16*)(base + 0);          // [0,16)   gemm2 out (h1 dead) -> agg2
  float* h2q   = (float*)(base + 16*MB);     // [16,24)  agg2 out f32 (h dead) -> ln1
  bf16*  qh    = (bf16*)(base + 24*MB);      // [24,28)  agg2 epilogue -> wv
  bf16*  ql    = (bf16*)(base + 28*MB);      // [28,32)
  bf16*  vh    = (bf16*)(base + 0);          // [0,4)    (h2f dead after agg2)
  bf16*  vl    = (bf16*)(base + 4*MB);       // [4,8)
  float* aobuf = (float*)(base + 8*MB);      // [8,16)
  float* y1    = (float*)(base + 24*MB);     // [24,32)  ln1 out (qh/ql dead after wv)
  bf16*  y1h   = (bf16*)(base + 0);          // [0,4)    (vh/vl dead after wo)
  bf16*  y1l   = (bf16*)(base + 4*MB);       // [4,8)
  bf16*  hidden= (bf16*)(base + 8*MB);       // [8,24)   16MB (aobuf,h2q dead after ln1)
  float* ffn2f = (float*)(base + 0);         // [0,8)    (y1h/l dead after ffn1)
  // S region [32,36): ~3.0 MB
  char* u = base + 32*MB;
  bf16* w1h = (bf16*)u; u += 131072;
  bf16* w2h = (bf16*)u; u += 524288;
  bf16* wvh = (bf16*)u; u += 32768;   bf16* wvl = (bf16*)u; u += 32768;
  bf16* woh = (bf16*)u; u += 32768;   bf16* wol = (bf16*)u; u += 32768;
  bf16* f1h = (bf16*)u; u += 131072;  bf16* f1l = (bf16*)u; u += 131072;
  bf16* f2h = (bf16*)u; u += 131072;  bf16* f2l = (bf16*)u; u += 131072;
  float* als  = (float*)u; u += (size_t)n*4*4;
  float* ald  = (float*)u; u += (size_t)n*4*4;
  int* offs   = (int*)u;   u += (size_t)(n+1)*4 + 252;
  unsigned short* csr = (unsigned short*)u; u += (size_t)tE*2;

  // ---- prep + CSR ----
  PrepArgs P = { x,W1,W2,wv,wo,f1,f2, xh,w1h,w2h,wvh,wvl,woh,wol,f1h,f1l,f2h,f2l };
  prep_kernel<<<(2588672+255)/256, 256, 0, stream>>>(P);
  zero_kernel<<<(n+255)/256, 256, 0, stream>>>(counts, n);
  count_kernel<<<(tE+255)/256, 256, 0, stream>>>(ei, counts, E);
  scan_kernel<<<1, 1024, 0, stream>>>(counts, offs, cursor);
  fill_kernel<<<(tE+255)/256, 256, 0, stream>>>(ei, cursor, csr, E);

  // ---- GAT layer 1 (single-bf16 operands; error attenuated by aggregation) ----
  mgemm<128,0,0,0,1,4><<<dim3(64,8), 256, 0, stream>>>(xh, nullptr, w1h, nullptr, nullptr, nullptr, h1, nullptr, 512);
  alsald_kernel<<<n, 256, 0, stream>>>(h1, a_src1, a_dst1, als, ald);
  gat_fused_kernel<true><<<n/4, 256, 0, stream>>>(h1, als, ald, offs, csr, b1, h, nullptr, nullptr);

  // ---- GAT layer 2 (single-bf16 operands) ----
  mgemm<512,0,0,0,1,4><<<dim3(64,8), 256, 0, stream>>>(h, nullptr, w2h, nullptr, nullptr, nullptr, h2f, nullptr, 512);
  alsald_kernel<<<n, 256, 0, stream>>>(h2f, a_src2, a_dst2, als, ald);
  gat_fused_kernel<false><<<n/4, 256, 0, stream>>>(h2f, als, ald, offs, csr, b2, h2q, qh, ql);

  // ---- temporal attention (collapsed to V at l=L-1) + head: split-precision tail ----
  mgemm<128,1,1,0,2,2><<<dim3(128,2), 128, 0, stream>>>(qh, ql, wvh, wvl, bv, nullptr, vh, vl, 128);
  mgemm<128,1,1,0,0,2><<<dim3(128,2), 128, 0, stream>>>(vh, vl, woh, wol, bo, aobuf, nullptr, nullptr, 128);
  ln_kernel<1><<<n/4, 256, 0, stream>>>(h2q, aobuf, ln_g, ln_b, y1, y1h, y1l);
  mgemm<128,1,1,1,1,4><<<dim3(64,8), 256, 0, stream>>>(y1h, y1l, f1h, f1l, fb1, nullptr, hidden, nullptr, 512);
  mgemm<512,0,1,0,0,2><<<dim3(128,2), 128, 0, stream>>>(hidden, nullptr, f2h, f2l, fb2, ffn2f, nullptr, nullptr, 128);
  ln_final_kernel<<<n/4, 256, 0, stream>>>(y1, ffn2f, ln_g, ln_b, wc, bc, outp);
}

// Round 18
// 299.243 us; speedup vs baseline: 1.1330x; 1.0655x over previous
//
#include <hip/hip_runtime.h>
#include <hip/hip_bf16.h>

#define NODES 16384
#define FEAT 512
typedef __hip_bfloat16 bf16;
typedef __hip_bfloat162 bf162;
typedef short short8v __attribute__((ext_vector_type(8)));
typedef float f32x4 __attribute__((ext_vector_type(4)));

static __device__ __forceinline__ float b2f(short s){
  return __uint_as_float(((unsigned)(unsigned short)s) << 16);
}
static __device__ __forceinline__ void split_store(bf16* h, bf16* l, size_t i, float v){
  bf16 hi = __float2bfloat16(v);
  h[i] = hi; l[i] = __float2bfloat16(v - __bfloat162float(hi));
}

// ---------------- diagnostic sentinel ----------------
__global__ void sentinel_kernel(float* __restrict__ out, int n, float v){
  int i = blockIdx.x*blockDim.x + threadIdx.x;
  if (i < n) out[i] = v;
}

// ---------------- CSR build ----------------
__global__ void zero_kernel(int* __restrict__ p, int n){
  int i = blockIdx.x*blockDim.x + threadIdx.x;
  if (i < n) p[i] = 0;
}
__global__ void count_kernel(const int* __restrict__ ei, int* __restrict__ counts, int E){
  int i = blockIdx.x*blockDim.x + threadIdx.x;
  if (i < 2*E){
    int dst = (i < E) ? ei[E+i] : ei[i-E];
    atomicAdd(&counts[dst], 1);
  }
}
__global__ __launch_bounds__(1024) void scan_kernel(const int* __restrict__ counts,
                                                    int* __restrict__ offs, int* __restrict__ cursor){
  __shared__ int sh[1024];
  const int t = threadIdx.x;
  int loc[16]; int s = 0;
#pragma unroll
  for (int i=0;i<16;i++){ loc[i] = counts[t*16+i]; s += loc[i]; }
  sh[t] = s; __syncthreads();
  for (int d=1; d<1024; d<<=1){
    int v = (t>=d) ? sh[t-d] : 0;
    __syncthreads(); sh[t] += v; __syncthreads();
  }
  int run = (t==0) ? 0 : sh[t-1];
#pragma unroll
  for (int i=0;i<16;i++){ offs[t*16+i] = run; cursor[t*16+i] = run; run += loc[i]; }
  if (t==1023) offs[NODES] = run;
}
__global__ void fill_kernel(const int* __restrict__ ei, int* __restrict__ cursor,
                            unsigned short* __restrict__ csr, int E){
  int i = blockIdx.x*blockDim.x + threadIdx.x;
  if (i < 2*E){
    int src = ei[i];
    int dst = (i < E) ? ei[E+i] : ei[i-E];
    int pos = atomicAdd(&cursor[dst], 1);
    csr[pos] = (unsigned short)src;
  }
}

// ---------------- prep ----------------
struct PrepArgs {
  const float *x,*W1,*W2,*wv,*wo,*f1,*f2;
  bf16 *xh,*w1h,*w2h,*wvh,*wvl,*woh,*wol,*f1h,*f1l,*f2h,*f2l;
};
__global__ void prep_kernel(PrepArgs P){
  int i = blockIdx.x*blockDim.x + threadIdx.x;
  if (i < 2097152){ P.xh[i] = __float2bfloat16(P.x[i]); return; }
  i -= 2097152;
  if (i < 65536){ P.w1h[i] = __float2bfloat16(P.W1[(i&127)*512 + (i>>7)]); return; }     // 128x512
  i -= 65536;
  if (i < 262144){ P.w2h[i] = __float2bfloat16(P.W2[(i&511)*512 + (i>>9)]); return; }    // 512x512
  i -= 262144;
  if (i < 16384){ split_store(P.wvh, P.wvl, i, P.wv[(i&127)*128 + (i>>7)]); return; }    // 128x128
  i -= 16384;
  if (i < 16384){ split_store(P.woh, P.wol, i, P.wo[(i&127)*128 + (i>>7)]); return; }
  i -= 16384;
  if (i < 65536){ split_store(P.f1h, P.f1l, i, P.f1[(i&127)*512 + (i>>7)]); return; }    // 128x512
  i -= 65536;
  if (i < 65536){ split_store(P.f2h, P.f2l, i, P.f2[(i&511)*128 + (i>>9)]); return; }    // 512x128
}

static __device__ __forceinline__ short8v ld8(const bf16* p){
  return *(const short8v*)(const void*)(p);
}

// ---------------- LDS-staged MFMA GEMM (m93-style): 128x128 block tile, 4 waves ----------------
// single bf16 operands, no bias/act, bf16 out. B stored transposed [N][K].
// LDS rows padded to 40 bf16 (80B): 16B-aligned ds_read_b128, 2-way-max bank aliasing (free).
// Per-acc MFMA order identical to mgemm -> bit-identical results.
template<int K>
__global__ __launch_bounds__(256) void lgemm(
    const bf16* __restrict__ A, const bf16* __restrict__ B,
    bf16* __restrict__ C, int N){
  __shared__ bf16 As[128*40];
  __shared__ bf16 Bs[128*40];
  const int tid = threadIdx.x;
  const int l = tid & 63, w = tid >> 6;
  const int lg = l >> 4, lr = l & 15;
  const int wr = w >> 1, wc = w & 1;
  const int r0 = blockIdx.x*128;       // row band; XCD = lin%8 = x%8 -> A band L2-resident
  const int c0 = blockIdx.y*128;
  const int srow = tid >> 1;           // staging: thread -> row, 16-bf16 half
  const int spos = (tid & 1) * 16;
  f32x4 acc[4][4] = {};
  const int ardA[4] = { (wr*64 +  0 + lr)*40 + lg*8, (wr*64 + 16 + lr)*40 + lg*8,
                        (wr*64 + 32 + lr)*40 + lg*8, (wr*64 + 48 + lr)*40 + lg*8 };
  const int brdB[4] = { (wc*64 +  0 + lr)*40 + lg*8, (wc*64 + 16 + lr)*40 + lg*8,
                        (wc*64 + 32 + lr)*40 + lg*8, (wc*64 + 48 + lr)*40 + lg*8 };
  const size_t agbase = (size_t)(r0 + srow)*K + spos;
  const size_t bgbase = (size_t)(c0 + srow)*K + spos;
  const int sl = srow*40 + spos;
#pragma unroll
  for (int k0 = 0; k0 < K; k0 += 32){
    // ---- stage A/B tiles (coalesced 16B loads, shared by all 4 waves) ----
    *(short8v*)&As[sl]     = ld8(A + agbase + k0);
    *(short8v*)&As[sl + 8] = ld8(A + agbase + k0 + 8);
    *(short8v*)&Bs[sl]     = ld8(B + bgbase + k0);
    *(short8v*)&Bs[sl + 8] = ld8(B + bgbase + k0 + 8);
    __syncthreads();
    short8v af[4], bfr[4];
#pragma unroll
    for (int f=0; f<4; f++){
      af[f]  = *(const short8v*)&As[ardA[f]];
      bfr[f] = *(const short8v*)&Bs[brdB[f]];
    }
#pragma unroll
    for (int fm=0; fm<4; fm++)
#pragma unroll
      for (int fn=0; fn<4; fn++)
        acc[fm][fn] = __builtin_amdgcn_mfma_f32_16x16x32_bf16(af[fm], bfr[fn], acc[fm][fn], 0,0,0);
    __syncthreads();
  }
#pragma unroll
  for (int fm=0; fm<4; fm++){
#pragma unroll
    for (int fn=0; fn<4; fn++){
      const int col = c0 + wc*64 + fn*16 + lr;
#pragma unroll
      for (int r=0; r<4; r++){
        const int row = r0 + wr*64 + fm*16 + lg*4 + r;
        C[(size_t)row*N + col] = __float2bfloat16(acc[fm][fn][r]);
      }
    }
  }
}

// ---------------- direct-reg MFMA GEMM (tail: split-precision small GEMMs) ----------------
template<int K, int SA, int SB, int ACT, int OMODE, int WPB>
__global__ __launch_bounds__(256) void mgemm(
    const bf16* __restrict__ Ah, const bf16* __restrict__ Al,
    const bf16* __restrict__ Bh, const bf16* __restrict__ Bl,
    const float* __restrict__ bias,
    float* __restrict__ Cf, bf16* __restrict__ Ch, bf16* __restrict__ Cl, int N){
  const int l = threadIdx.x & 63, w = threadIdx.x >> 6;
  const int lg = l >> 4, lr = l & 15;
  const int r0 = (blockIdx.x*WPB + w)*64;
  const int c0 = blockIdx.y*64;
  f32x4 acc[4][4] = {};
  int abase[4], bbase[4];
#pragma unroll
  for (int f=0; f<4; f++){
    abase[f] = (r0 + f*16 + lr)*K + lg*8;
    bbase[f] = (c0 + f*16 + lr)*K + lg*8;
  }
#pragma unroll
  for (int k0 = 0; k0 < K; k0 += 32){
    short8v ah[4], alo[4], bh[4], blo[4];
#pragma unroll
    for (int f=0; f<4; f++){
      ah[f] = ld8(Ah + abase[f] + k0);
      if (SA) alo[f] = ld8(Al + abase[f] + k0);
      bh[f] = ld8(Bh + bbase[f] + k0);
      if (SB) blo[f] = ld8(Bl + bbase[f] + k0);
    }
#pragma unroll
    for (int fm=0; fm<4; fm++)
#pragma unroll
      for (int fn=0; fn<4; fn++){
        acc[fm][fn] = __builtin_amdgcn_mfma_f32_16x16x32_bf16(ah[fm], bh[fn], acc[fm][fn], 0,0,0);
        if (SB) acc[fm][fn] = __builtin_amdgcn_mfma_f32_16x16x32_bf16(ah[fm], blo[fn], acc[fm][fn], 0,0,0);
        if (SA) acc[fm][fn] = __builtin_amdgcn_mfma_f32_16x16x32_bf16(alo[fm], bh[fn], acc[fm][fn], 0,0,0);
      }
  }
#pragma unroll
  for (int fm=0; fm<4; fm++){
#pragma unroll
    for (int fn=0; fn<4; fn++){
      const int col = c0 + fn*16 + lr;
      const float bv = bias ? bias[col] : 0.f;
#pragma unroll
      for (int r=0; r<4; r++){
        const int row = r0 + fm*16 + lg*4 + r;
        float v = acc[fm][fn][r] + bv;
        if (ACT==1) v = fmaxf(v, 0.f);
        const size_t idx = (size_t)row*N + col;
        if (OMODE==0) Cf[idx] = v;
        else if (OMODE==1) Ch[idx] = __float2bfloat16(v);
        else split_store(Ch, Cl, idx, v);
      }
    }
  }
}

// ---------------- attention coefficients ----------------
__global__ __launch_bounds__(256) void alsald_kernel(const bf16* __restrict__ h,
    const float* __restrict__ a_s, const float* __restrict__ a_d,
    float* __restrict__ als, float* __restrict__ ald){
  int n = blockIdx.x;
  int w = threadIdx.x >> 6, lane = threadIdx.x & 63;
  int c = w*128 + lane*2;
  bf162 hv = *(const bf162*)&h[(size_t)n*FEAT + c];
  float hx = __bfloat162float(hv.x), hy = __bfloat162float(hv.y);
  float2 as2 = *(const float2*)&a_s[c];
  float2 ad2 = *(const float2*)&a_d[c];
  float s = hx*as2.x + hy*as2.y;
  float d = hx*ad2.x + hy*ad2.y;
#pragma unroll
  for (int o=32;o>0;o>>=1){ s += __shfl_xor(s,o); d += __shfl_xor(d,o); }
  if (lane == 0){ als[n*4+w] = s; ald[n*4+w] = d; }
}

// ---------------- fused GAT aggregation (r17: packed alpha, 2-deep pipeline) ----------------
template<bool CONCAT>
__global__ __launch_bounds__(256) void gat_fused_kernel(const bf16* __restrict__ hfeat,
    const float* __restrict__ als, const float* __restrict__ ald,
    const int* __restrict__ offs, const unsigned short* __restrict__ csr,
    const float* __restrict__ bias, void* __restrict__ outv,
    bf16* __restrict__ qh, bf16* __restrict__ ql){
  const int w = threadIdx.x >> 6, l = threadIdx.x & 63, g = l >> 4, s16 = l & 15;
  const int nb = blockIdx.x;
  const int n = (nb & 7)*2048 + (nb >> 3)*4 + w;   // cluster-contiguous, XCD-aligned
  const float adg = ald[(size_t)n*4 + g];
  const int beg = offs[n];
  const int cnt = offs[n+1] - beg + 1;             // + implicit self-loop (edge cnt-1)
  float ev[6]; int sv[6];
#pragma unroll
  for (int p=0;p<6;p++){
    const int i = s16 + p*16;
    int src = n;
    float e = -1e30f;
    if (i < cnt){
      if (i < cnt-1) src = (int)csr[beg+i];
      float t = als[(size_t)src*4+g] + adg;
      e = fmaxf(t, 0.2f*t);                        // leaky_relu 0.2
    }
    ev[p] = e; sv[p] = src;
  }
  float m = -1e30f;
#pragma unroll
  for (int p=0;p<6;p++) m = fmaxf(m, ev[p]);
  float den = 0.f;
#pragma unroll
  for (int p=0;p<6;p++) den += (ev[p] > -1e29f) ? __expf(ev[p]-m) : 0.f;
#pragma unroll
  for (int mask=1; mask<16; mask<<=1){
    float mo = __shfl_xor(m, mask);
    float dd = __shfl_xor(den, mask);
    float nm = fmaxf(m, mo);
    den = den*__expf(m-nm) + dd*__expf(mo-nm);
    m = nm;
  }
  const float C = __expf(-m)/(den + 1e-16f);
  int pk[6];
#pragma unroll
  for (int p=0;p<6;p++){
    float a = (ev[p] > -1e29f) ? __expf(ev[p])*C : 0.f;
    bf16 ab = __float2bfloat16(a);
    pk[p] = ((int)*(unsigned short*)&ab << 16) | (sv[p] & 0xFFFF);
  }
  float acc[8] = {0,0,0,0,0,0,0,0};
  const int fb = l*8;
  const bf16* hp = hfeat + fb;
#pragma unroll
  for (int p=0;p<6;p++){
    const int pbase = p*16;
    if (pbase < cnt){
      const int lim = (cnt - pbase < 16) ? (cnt - pbase) : 16;
      int u_c = __shfl(pk[p], (l & 48));
      short8v hv_c = *(const short8v*)(const void*)(hp + (size_t)(u_c & 0xFFFF)*FEAT);
      for (int j=1; j<lim; ++j){
        const int u_n = __shfl(pk[p], (l & 48) | j);
        const short8v hv_n = *(const short8v*)(const void*)(hp + (size_t)(u_n & 0xFFFF)*FEAT);
        const float a_c = __uint_as_float((unsigned)u_c & 0xFFFF0000u);
#pragma unroll
        for (int k=0;k<8;k++) acc[k] += a_c * b2f(hv_c[k]);
        u_c = u_n; hv_c = hv_n;
      }
      const float a_c = __uint_as_float((unsigned)u_c & 0xFFFF0000u);
#pragma unroll
      for (int k=0;k<8;k++) acc[k] += a_c * b2f(hv_c[k]);
    }
  }
  for (int i = 96; i < cnt; ++i){
    const int src = (i < cnt-1) ? (int)csr[beg+i] : n;
    float t = als[(size_t)src*4+g] + adg;
    t = fmaxf(t, 0.2f*t);
    const float a = __expf(t)*C;
    const short8v hv = *(const short8v*)(const void*)&hfeat[(size_t)src*FEAT + fb];
#pragma unroll
    for (int k=0;k<8;k++) acc[k] += a * b2f(hv[k]);
  }
  if (CONCAT){
    short8v ov;
#pragma unroll
    for (int j=0;j<8;j++){
      float v = acc[j] + bias[fb+j];
      v = v > 0.f ? v : expm1f(v);               // fused ELU
      bf16 bv = __float2bfloat16(v);
      ov[j] = (short)*(unsigned short*)&bv;
    }
    *(short8v*)((char*)outv + ((size_t)n*FEAT + fb)*2) = ov;
  } else {
#pragma unroll
    for (int j=0;j<8;j++){
      acc[j] += __shfl_xor(acc[j], 16);
      acc[j] += __shfl_xor(acc[j], 32);
    }
    if (l < 16){
      float* op = (float*)outv + (size_t)n*128 + l*8;
#pragma unroll
      for (int j=0;j<8;j++){
        const int col = l*8 + j;
        float v = 0.25f*acc[j] + bias[col];
        float ex = __expf((float)(col & ~1) * (-9.210340371976184f/128.f));
        float pe = (col & 1) ? cosf(4.f*ex) : sinf(4.f*ex);
        float q = v + pe;
        op[j] = q;
        split_store(qh, ql, (size_t)n*128 + col, q);
      }
    }
  }
}

// ---------------- LayerNorm(a+b), optional bf16 split output ----------------
template<int SPLIT>
__global__ __launch_bounds__(256) void ln_kernel(const float* __restrict__ a, const float* __restrict__ b,
    const float* __restrict__ g, const float* __restrict__ bb, float* __restrict__ out,
    bf16* __restrict__ oh, bf16* __restrict__ ol){
  int row = blockIdx.x*4 + (threadIdx.x >> 6);
  int lane = threadIdx.x & 63;
  int c = lane*2;
  float2 va = *(const float2*)&a[(size_t)row*128 + c];
  float2 vb = *(const float2*)&b[(size_t)row*128 + c];
  float x0 = va.x+vb.x, x1 = va.y+vb.y;
  float s = x0+x1, q = x0*x0 + x1*x1;
#pragma unroll
  for (int o=32;o>0;o>>=1){ s += __shfl_xor(s,o); q += __shfl_xor(q,o); }
  float mu = s*(1.f/128.f);
  float var = q*(1.f/128.f) - mu*mu;
  float r = 1.f/sqrtf(var + 1e-5f);
  float y0 = (x0-mu)*r*g[c]   + bb[c];
  float y1 = (x1-mu)*r*g[c+1] + bb[c+1];
  size_t idx = (size_t)row*128 + c;
  out[idx] = y0; out[idx+1] = y1;
  if (SPLIT){ split_store(oh, ol, idx, y0); split_store(oh, ol, idx+1, y1); }
}

// ---------------- fused LayerNorm2 + classifier head ----------------
__global__ __launch_bounds__(256) void ln_final_kernel(const float* __restrict__ a, const float* __restrict__ b,
    const float* __restrict__ g, const float* __restrict__ bb,
    const float* __restrict__ wc, const float* __restrict__ bc,
    float* __restrict__ out){
  int row = blockIdx.x*4 + (threadIdx.x >> 6);
  int lane = threadIdx.x & 63;
  int c = lane*2;
  float2 va = *(const float2*)&a[(size_t)row*128 + c];
  float2 vb = *(const float2*)&b[(size_t)row*128 + c];
  float x0 = va.x+vb.x, x1 = va.y+vb.y;
  float s = x0+x1, q = x0*x0 + x1*x1;
#pragma unroll
  for (int o=32;o>0;o>>=1){ s += __shfl_xor(s,o); q += __shfl_xor(q,o); }
  float mu = s*(1.f/128.f);
  float var = q*(1.f/128.f) - mu*mu;
  float r = 1.f/sqrtf(var + 1e-5f);
  float y0 = (x0-mu)*r*g[c]   + bb[c];
  float y1 = (x1-mu)*r*g[c+1] + bb[c+1];
  float s0 = y0*wc[c*2]   + y1*wc[(c+1)*2];
  float s1 = y0*wc[c*2+1] + y1*wc[(c+1)*2+1];
#pragma unroll
  for (int o=32;o>0;o>>=1){ s0 += __shfl_xor(s0,o); s1 += __shfl_xor(s1,o); }
  if (lane == 0){
    out[row*2]   = s0 + bc[0];
    out[row*2+1] = s1 + bc[1];
  }
}

extern "C" void kernel_launch(void* const* d_in, const int* in_sizes, int n_in,
                              void* d_out, int out_size, void* d_ws, size_t ws_size,
                              hipStream_t stream){
  const float* x      = (const float*)d_in[0];
  const int*   ei     = (const int*)d_in[1];
  const float* W1     = (const float*)d_in[3];
  const float* a_src1 = (const float*)d_in[4];
  const float* a_dst1 = (const float*)d_in[5];
  const float* b1     = (const float*)d_in[6];
  const float* W2     = (const float*)d_in[7];
  const float* a_src2 = (const float*)d_in[8];
  const float* a_dst2 = (const float*)d_in[9];
  const float* b2     = (const float*)d_in[10];
  const float* wv     = (const float*)d_in[15];
  const float* bv     = (const float*)d_in[16];
  const float* wo     = (const float*)d_in[17];
  const float* bo     = (const float*)d_in[18];
  const float* ln_g   = (const float*)d_in[19];
  const float* ln_b   = (const float*)d_in[20];
  const float* f1     = (const float*)d_in[21];
  const float* fb1    = (const float*)d_in[22];
  const float* f2     = (const float*)d_in[23];
  const float* fb2    = (const float*)d_in[24];
  const float* wc     = (const float*)d_in[25];
  const float* bc     = (const float*)d_in[26];
  float* outp = (float*)d_out;

  const int E = in_sizes[1] / 2;
  const int n = NODES;
  const int tE = 2*E;
  const size_t MB = 1024*1024;

  const size_t NEED = 36*MB;
  if (ws_size < NEED){
    sentinel_kernel<<<(out_size+255)/256, 256, 0, stream>>>(outp, out_size,
        1000.0f + (float)(ws_size / MB));
    return;
  }

  // ---- arena [0,36) MB; liveness audited phase-by-phase ----
  char* base = (char*)d_ws;
  int* counts = (int*)(base + 0);            // [0,64K)   pre-gemm1 only
  int* cursor = (int*)(base + 65536);        // [64K,128K)
  bf16*  h1    = (bf16*)(base + 0);          // [0,16)   gemm1 out -> agg1
  bf16*  xh    = (bf16*)(base + 16*MB);      // [16,20)  prep -> gemm1
  bf16*  h     = (bf16*)(base + 16*MB);      // [16,32)  agg1 out (xh dead) -> gemm2
  bf16*  h2f   = (bf16*)(base + 0);          // [0,16)   gemm2 out (h1 dead) -> agg2
  float* h2q   = (float*)(base + 16*MB);     // [16,24)  agg2 out f32 (h dead) -> ln1
  bf16*  qh    = (bf16*)(base + 24*MB);      // [24,28)  agg2 epilogue -> wv
  bf16*  ql    = (bf16*)(base + 28*MB);      // [28,32)
  bf16*  vh    = (bf16*)(base + 0);          // [0,4)    (h2f dead after agg2)
  bf16*  vl    = (bf16*)(base + 4*MB);       // [4,8)
  float* aobuf = (float*)(base + 8*MB);      // [8,16)
  float* y1    = (float*)(base + 24*MB);     // [24,32)  ln1 out (qh/ql dead after wv)
  bf16*  y1h   = (bf16*)(base + 0);          // [0,4)    (vh/vl dead after wo)
  bf16*  y1l   = (bf16*)(base + 4*MB);       // [4,8)
  bf16*  hidden= (bf16*)(base + 8*MB);       // [8,24)   16MB (aobuf,h2q dead after ln1)
  float* ffn2f = (float*)(base + 0);         // [0,8)    (y1h/l dead after ffn1)
  // S region [32,36): ~3.0 MB
  char* u = base + 32*MB;
  bf16* w1h = (bf16*)u; u += 131072;
  bf16* w2h = (bf16*)u; u += 524288;
  bf16* wvh = (bf16*)u; u += 32768;   bf16* wvl = (bf16*)u; u += 32768;
  bf16* woh = (bf16*)u; u += 32768;   bf16* wol = (bf16*)u; u += 32768;
  bf16* f1h = (bf16*)u; u += 131072;  bf16* f1l = (bf16*)u; u += 131072;
  bf16* f2h = (bf16*)u; u += 131072;  bf16* f2l = (bf16*)u; u += 131072;
  float* als  = (float*)u; u += (size_t)n*4*4;
  float* ald  = (float*)u; u += (size_t)n*4*4;
  int* offs   = (int*)u;   u += (size_t)(n+1)*4 + 252;
  unsigned short* csr = (unsigned short*)u; u += (size_t)tE*2;

  // ---- prep + CSR ----
  PrepArgs P = { x,W1,W2,wv,wo,f1,f2, xh,w1h,w2h,wvh,wvl,woh,wol,f1h,f1l,f2h,f2l };
  prep_kernel<<<(2588672+255)/256, 256, 0, stream>>>(P);
  zero_kernel<<<(n+255)/256, 256, 0, stream>>>(counts, n);
  count_kernel<<<(tE+255)/256, 256, 0, stream>>>(ei, counts, E);
  scan_kernel<<<1, 1024, 0, stream>>>(counts, offs, cursor);
  fill_kernel<<<(tE+255)/256, 256, 0, stream>>>(ei, cursor, csr, E);

  // ---- GAT layer 1 (LDS-staged big GEMM) ----
  lgemm<128><<<dim3(128,4), 256, 0, stream>>>(xh, w1h, h1, 512);
  alsald_kernel<<<n, 256, 0, stream>>>(h1, a_src1, a_dst1, als, ald);
  gat_fused_kernel<true><<<n/4, 256, 0, stream>>>(h1, als, ald, offs, csr, b1, h, nullptr, nullptr);

  // ---- GAT layer 2 (LDS-staged big GEMM) ----
  lgemm<512><<<dim3(128,4), 256, 0, stream>>>(h, w2h, h2f, 512);
  alsald_kernel<<<n, 256, 0, stream>>>(h2f, a_src2, a_dst2, als, ald);
  gat_fused_kernel<false><<<n/4, 256, 0, stream>>>(h2f, als, ald, offs, csr, b2, h2q, qh, ql);

  // ---- temporal attention (collapsed to V at l=L-1) + head: split-precision tail ----
  mgemm<128,1,1,0,2,2><<<dim3(128,2), 128, 0, stream>>>(qh, ql, wvh, wvl, bv, nullptr, vh, vl, 128);
  mgemm<128,1,1,0,0,2><<<dim3(128,2), 128, 0, stream>>>(vh, vl, woh, wol, bo, aobuf, nullptr, nullptr, 128);
  ln_kernel<1><<<n/4, 256, 0, stream>>>(h2q, aobuf, ln_g, ln_b, y1, y1h, y1l);
  mgemm<128,1,1,1,1,4><<<dim3(64,8), 256, 0, stream>>>(y1h, y1l, f1h, f1l, fb1, nullptr, hidden, nullptr, 512);
  mgemm<512,0,1,0,0,2><<<dim3(128,2), 128, 0, stream>>>(hidden, nullptr, f2h, f2l, fb2, ffn2f, nullptr, nullptr, 128);
  ln_final_kernel<<<n/4, 256, 0, stream>>>(y1, ffn2f, ln_g, ln_b, wc, bc, outp);
}